// Round 4
// baseline (236.385 us; speedup 1.0000x reference)
//
#include <hip/hip_runtime.h>
#include <hip/hip_bf16.h>

// GAT layer for MI355X (gfx950). FP32 in/out.
//   K1 gat_wh   : Wh = h @ W^T via split-bf16 MFMA -> WhT_hi/lo[128][8192] bf16.
//   K2 gat_f12  : f1/f2 row/col logits (fp32, pre-scaled by log2e).
//   K3 gat_flash: BARRIER-FREE per-wave flash softmax+PV. Each wave loads adj
//                 directly in MFMA A-fragment layout (16 rows x 128B segments),
//                 computes p = adj ? exp2(lrelu) : 0 in-register, MFMAs against
//                 WhT hi/lo. 16 independent waves/CU (2 col-halves x 8 k-slices
//                 over 32 rows); LDS used only for the phased k-split reduction
//                 at the end. R3 post-mortem: lockstep barriers + in-order vmcnt
//                 capped adj at 1 TB/s; this removes both.

typedef __bf16 bf16;
typedef __attribute__((ext_vector_type(8))) __bf16 bf16x8;
typedef __attribute__((ext_vector_type(4))) float f32x4;

#define NN 8192
#define F_IN 256
#define F_OUT 128
#define LOG2E 1.44269504088896f
#define ALPHA 0.2f

__device__ __forceinline__ void split8(const float* __restrict__ p,
                                       bf16x8& hi, bf16x8& lo) {
    const float4 u = *(const float4*)p;
    const float4 v = *(const float4*)(p + 4);
    float f[8] = {u.x, u.y, u.z, u.w, v.x, v.y, v.z, v.w};
#pragma unroll
    for (int j = 0; j < 8; ++j) {
        const bf16 h = (bf16)f[j];
        hi[j] = h;
        lo[j] = (bf16)(f[j] - (float)h);
    }
}

// ---------------------------------------------------------------------------
// K1: Wh = h @ W^T (8192x128, K=256) -> transposed bf16 planes.
// 256 blocks x 128 thr (2 waves x 16 rows).
// ---------------------------------------------------------------------------
__global__ __launch_bounds__(128) void gat_wh(const float* __restrict__ h,
                                              const float* __restrict__ W,
                                              bf16* __restrict__ WhT_hi,
                                              bf16* __restrict__ WhT_lo) {
    const int tid = threadIdx.x;
    const int wv = tid >> 6;
    const int l15 = tid & 15;
    const int g = (tid & 63) >> 4;
    const int rowbase = blockIdx.x * 32 + wv * 16;

    f32x4 acc[8];
    const f32x4 zz = {0.f, 0.f, 0.f, 0.f};
#pragma unroll
    for (int nf = 0; nf < 8; ++nf) acc[nf] = zz;

#pragma unroll
    for (int ks = 0; ks < 8; ++ks) {
        const int k = ks * 32 + g * 8;
        bf16x8 ah, al;
        split8(h + (size_t)(rowbase + l15) * F_IN + k, ah, al);
#pragma unroll
        for (int nf = 0; nf < 8; ++nf) {
            bf16x8 bh, bl;
            split8(W + (size_t)(nf * 16 + l15) * F_IN + k, bh, bl);
            acc[nf] = __builtin_amdgcn_mfma_f32_16x16x32_bf16(ah, bh, acc[nf], 0, 0, 0);
            acc[nf] = __builtin_amdgcn_mfma_f32_16x16x32_bf16(ah, bl, acc[nf], 0, 0, 0);
            acc[nf] = __builtin_amdgcn_mfma_f32_16x16x32_bf16(al, bh, acc[nf], 0, 0, 0);
        }
    }

#pragma unroll
    for (int nf = 0; nf < 8; ++nf)
#pragma unroll
        for (int r = 0; r < 4; ++r) {
            const int row = rowbase + g * 4 + r;
            const int c = nf * 16 + l15;
            const float val = acc[nf][r];
            const bf16 vh = (bf16)val;
            WhT_hi[(size_t)c * NN + row] = vh;
            WhT_lo[(size_t)c * NN + row] = (bf16)(val - (float)vh);
        }
}

// ---------------------------------------------------------------------------
// K2: f1/f2 (fp32, pre-scaled by log2e). Coalesced column reads of WhT.
// ---------------------------------------------------------------------------
__global__ __launch_bounds__(64) void gat_f12(const bf16* __restrict__ WhT_hi,
                                              const bf16* __restrict__ WhT_lo,
                                              const float* __restrict__ a,
                                              float* __restrict__ f1L,
                                              float* __restrict__ f2L) {
    const int i = blockIdx.x * 64 + threadIdx.x;
    float s1 = 0.f, s2 = 0.f;
#pragma unroll 8
    for (int c = 0; c < F_OUT; ++c) {
        const float wh = (float)WhT_hi[(size_t)c * NN + i] +
                         (float)WhT_lo[(size_t)c * NN + i];
        s1 += wh * a[c];
        s2 += wh * a[F_OUT + c];
    }
    f1L[i] = s1 * LOG2E;
    f2L[i] = s2 * LOG2E;
}

// ---------------------------------------------------------------------------
// K3: barrier-free flash. 256 blocks x 1024 thr (16 waves).
// Wave (ch, kq): rows [32b,32b+32), cols [64ch,64ch+64), k in [1024kq,+1024).
// Per k-step (32): adj loaded in A-frag layout (lane l: row l&15 / +16,
// k = 8*(l>>4)+j — same bijection as B-frags -> k-slot-order agnostic),
// p computed in-register, 16 MFMAs. adj double-buffered 1 k-step ahead;
// no barriers in the main loop. Epilogue: 8 LDS phases sum the k-split,
// rowsum likewise (from bf16-rounded p, same weights as MFMA numerator).
// ---------------------------------------------------------------------------
__global__ __launch_bounds__(1024) void gat_flash(const int* __restrict__ adj,
                                                  const bf16* __restrict__ WhT_hi,
                                                  const bf16* __restrict__ WhT_lo,
                                                  const float* __restrict__ f1L,
                                                  const float* __restrict__ f2L,
                                                  float* __restrict__ out) {
    __shared__ float accL[32][128];
    __shared__ float rsL[32];

    const int tid = threadIdx.x;
    const int wv = tid >> 6;   // 0..15
    const int ch = wv >> 3;    // col half
    const int kq = wv & 7;     // k slice
    const int l = tid & 63;
    const int l15 = l & 15;
    const int g = l >> 4;
    const int r0 = blockIdx.x * 32;

    const int kbase = kq * 1024;
    const float f1a = f1L[r0 + l15];
    const float f1b = f1L[r0 + 16 + l15];

    const int* arA = adj + (size_t)(r0 + l15) * NN + kbase + g * 8;
    const int* arB = arA + (size_t)16 * NN;
    const float* f2p = f2L + kbase + g * 8;
    const bf16* bhp = WhT_hi + (size_t)(ch * 64 + l15) * NN + kbase + g * 8;
    const bf16* blp = WhT_lo + (size_t)(ch * 64 + l15) * NN + kbase + g * 8;

    f32x4 accA[4], accB[4];
    const f32x4 zz = {0.f, 0.f, 0.f, 0.f};
#pragma unroll
    for (int ct = 0; ct < 4; ++ct) { accA[ct] = zz; accB[ct] = zz; }
    float rsa = 0.f, rsb = 0.f;

    // prefetch k-step 0 adjacency
    int4 a0 = *(const int4*)(arA);
    int4 a1 = *(const int4*)(arA + 4);
    int4 b0 = *(const int4*)(arB);
    int4 b1 = *(const int4*)(arB + 4);

    for (int t = 0; t < 32; ++t) {
        // prefetch next k-step's adj (wrap on last iter: harmless reload)
        const int noff = ((t + 1) & 31) * 32;
        int4 na0 = *(const int4*)(arA + noff);
        int4 na1 = *(const int4*)(arA + noff + 4);
        int4 nb0 = *(const int4*)(arB + noff);
        int4 nb1 = *(const int4*)(arB + noff + 4);

        const int koff = t * 32;
        const float4 f2a = *(const float4*)(f2p + koff);
        const float4 f2b = *(const float4*)(f2p + koff + 4);

        const int aa[8] = {a0.x, a0.y, a0.z, a0.w, a1.x, a1.y, a1.z, a1.w};
        const int ab[8] = {b0.x, b0.y, b0.z, b0.w, b1.x, b1.y, b1.z, b1.w};
        const float ff[8] = {f2a.x, f2a.y, f2a.z, f2a.w, f2b.x, f2b.y, f2b.z, f2b.w};

        bf16x8 pa, pb;
#pragma unroll
        for (int j = 0; j < 8; ++j) {
            const float xa = f1a + ff[j];
            const float xb = f1b + ff[j];
            const float ea = __builtin_amdgcn_exp2f(fmaxf(xa, ALPHA * xa));
            const float eb = __builtin_amdgcn_exp2f(fmaxf(xb, ALPHA * xb));
            pa[j] = (bf16)(aa[j] > 0 ? ea : 0.f);
            pb[j] = (bf16)(ab[j] > 0 ? eb : 0.f);
        }
        // rowsum from the SAME bf16-rounded weights the MFMA consumes
#pragma unroll
        for (int j = 0; j < 8; ++j) {
            rsa += (float)pa[j];
            rsb += (float)pb[j];
        }

#pragma unroll
        for (int ct = 0; ct < 4; ++ct) {
            const bf16x8 bh = *(const bf16x8*)(bhp + (size_t)ct * 16 * NN + koff);
            const bf16x8 bl = *(const bf16x8*)(blp + (size_t)ct * 16 * NN + koff);
            accA[ct] = __builtin_amdgcn_mfma_f32_16x16x32_bf16(pa, bh, accA[ct], 0, 0, 0);
            accA[ct] = __builtin_amdgcn_mfma_f32_16x16x32_bf16(pa, bl, accA[ct], 0, 0, 0);
            accB[ct] = __builtin_amdgcn_mfma_f32_16x16x32_bf16(pb, bh, accB[ct], 0, 0, 0);
            accB[ct] = __builtin_amdgcn_mfma_f32_16x16x32_bf16(pb, bl, accB[ct], 0, 0, 0);
        }

        a0 = na0; a1 = na1; b0 = nb0; b1 = nb1;
    }

    // rowsum across the 4 k-groups of this wave (rows l&15 / l&15+16)
    rsa += __shfl_xor(rsa, 16);
    rsa += __shfl_xor(rsa, 32);
    rsb += __shfl_xor(rsb, 16);
    rsb += __shfl_xor(rsb, 32);

    // phased k-split reduction. D layout (m89): row = 4*(l>>4)+reg, col = l&15.
    for (int ph = 0; ph < 8; ++ph) {
        if (kq == ph) {
            const int colb = ch * 64 + l15;
#pragma unroll
            for (int ct = 0; ct < 4; ++ct)
#pragma unroll
                for (int r = 0; r < 4; ++r) {
                    const int col = colb + ct * 16;
                    const int rowA = g * 4 + r;
                    const int rowB = 16 + g * 4 + r;
                    if (ph == 0) {
                        accL[rowA][col] = accA[ct][r];
                        accL[rowB][col] = accB[ct][r];
                    } else {
                        accL[rowA][col] += accA[ct][r];
                        accL[rowB][col] += accB[ct][r];
                    }
                }
            if (ch == 0 && l < 16) {
                if (ph == 0) {
                    rsL[l15] = rsa;
                    rsL[16 + l15] = rsb;
                } else {
                    rsL[l15] += rsa;
                    rsL[16 + l15] += rsb;
                }
            }
        }
        __syncthreads();
    }

    // divide + store: 1024 thr x 4 floats = 32x128 tile
    const int e = tid * 4;
    const int row = e >> 7;
    const int col = e & 127;
    const float inv = 1.0f / rsL[row];
    float4 v = *(const float4*)&accL[row][col];
    v.x *= inv; v.y *= inv; v.z *= inv; v.w *= inv;
    *(float4*)(out + (size_t)(r0 + row) * F_OUT + col) = v;
}

// ---------------------------------------------------------------------------
extern "C" void kernel_launch(void* const* d_in, const int* in_sizes, int n_in,
                              void* d_out, int out_size, void* d_ws, size_t ws_size,
                              hipStream_t stream) {
    const float* h = (const float*)d_in[0];  // (8192, 256) fp32
    const int* adj = (const int*)d_in[1];    // (8192, 8192) int32
    const float* W = (const float*)d_in[2];  // (128, 256) fp32
    const float* a = (const float*)d_in[3];  // (1, 256) fp32
    float* out = (float*)d_out;              // (8192, 128) fp32

    char* ws = (char*)d_ws;
    bf16* WhT_hi = (bf16*)ws;                              // 2 MB
    bf16* WhT_lo = (bf16*)(ws + (size_t)2 * 1024 * 1024);  // 2 MB
    float* f1L = (float*)(ws + (size_t)4 * 1024 * 1024);   // 32 KB
    float* f2L = f1L + NN;                                 // 32 KB

    gat_wh<<<256, 128, 0, stream>>>(h, W, WhT_hi, WhT_lo);
    gat_f12<<<NN / 64, 64, 0, stream>>>(WhT_hi, WhT_lo, a, f1L, f2L);
    gat_flash<<<NN / 32, 1024, 0, stream>>>(adj, WhT_hi, WhT_lo, f1L, f2L, out);
}